// Round 19
// baseline (61.346 us; speedup 1.0000x reference)
//
#include <hip/hip_runtime.h>
#include <float.h>

#define BATCH 4

typedef _Float16 half4v __attribute__((ext_vector_type(4)));
typedef _Float16 half8 __attribute__((ext_vector_type(8)));
typedef float f32x16 __attribute__((ext_vector_type(16)));
typedef float f32x2 __attribute__((ext_vector_type(2)));

// ================= MFMA K=8 path (R19 = elementwise-min accumulate) ========
// E[j,i] = qs_j - 2 q_j . h_pi   via K=8 fp16 slots:
//  A[j] (scan side) = [hqx,hqy,hqz, eqx,eqy,eqz, qs_h, qs_e]
//  B[i] (held side) = [-2hpx,-2hpy,-2hpz, -2hpx,-2hpy,-2hpz, 1, 1]
// D[j,i] = E + |p_i|^2 added in fp32 in the EPILOGUE. Dropped -2q.e_p ~1.6e-2
// << 0.0675 threshold (R16/R18 measured absmax 0.0156).
//
// R19 change: the per-MFMA 8-op min3 TREE (serial scalar chain dependent on
// a ~30cyc-latency MFMA result, 524K times) is replaced by 16 INDEPENDENT
// elementwise v_min into a vector accumulator; horizontal fold happens once
// per wave in the epilogue. IT 4->2 keeps VGPR ~82 (<128 cliff) -> 8
// waves/SIMD, double R16's residency.

__global__ void prep_k8(const float* __restrict__ x1, const float* __restrict__ x2,
                        _Float16* __restrict__ pa1, _Float16* __restrict__ pb1, float* __restrict__ ps1,
                        _Float16* __restrict__ pa2, _Float16* __restrict__ pb2, float* __restrict__ ps2,
                        float* __restrict__ out, int n1, int n2, int outn) {
    const int i = blockIdx.x * blockDim.x + threadIdx.x;
    const _Float16 one = (_Float16)1.0f;

    #pragma unroll
    for (int which = 0; which < 2; ++which) {
        const int n = which ? n2 : n1;
        if (i >= n) continue;
        const float* xp = (which ? x2 : x1) + 3 * (size_t)i;
        _Float16* pa = (which ? pa2 : pa1) + 8 * (size_t)i;
        _Float16* pb = (which ? pb2 : pb1) + 8 * (size_t)i;
        float* ps    = (which ? ps2 : ps1);

        const float x = xp[0], y = xp[1], z = xp[2];
        const _Float16 hx = (_Float16)x, hy = (_Float16)y, hz = (_Float16)z;
        const _Float16 ex = (_Float16)(x - (float)hx);
        const _Float16 ey = (_Float16)(y - (float)hy);
        const _Float16 ez = (_Float16)(z - (float)hz);
        const float sq = fmaf(x, x, fmaf(y, y, z * z));
        const _Float16 qh = (_Float16)sq;
        const _Float16 qe = (_Float16)(sq - (float)qh);
        const _Float16 tx = (_Float16)(-2.0f * (float)hx);
        const _Float16 ty = (_Float16)(-2.0f * (float)hy);
        const _Float16 tz = (_Float16)(-2.0f * (float)hz);

        *(half8*)pa = (half8){hx, hy, hz, ex, ey, ez, qh, qe};   // A-form, 16B
        *(half8*)pb = (half8){tx, ty, tz, tx, ty, tz, one, one}; // B-form, 16B
        ps[i] = sq;                                              // fp32 exact
    }
    if (i < outn) out[i] = FLT_MAX;
}

// Horizontal fold of a 16-wide accumulator: used ONCE per wave (epilogue).
__device__ inline float fold16(const f32x16 d) {
    const float t0 = fminf(fminf(d[0],  d[1]),  d[2]);
    const float t1 = fminf(fminf(d[3],  d[4]),  d[5]);
    const float t2 = fminf(fminf(d[6],  d[7]),  d[8]);
    const float t3 = fminf(fminf(d[9],  d[10]), d[11]);
    const float t4 = fminf(fminf(d[12], d[13]), d[14]);
    const float u0 = fminf(fminf(t0, t1), t2);
    const float u1 = fminf(fminf(t3, t4), d[15]);
    return fminf(u0, u1);
}

// R19: LDS-free (R13-proven), K=8, IT=2, elementwise-min vector accumulate.
template<int NJ>
__global__ __launch_bounds__(256) void chamfer_k8(
        const _Float16* __restrict__ pa1, const _Float16* __restrict__ pb1,
        const float* __restrict__ ps1,
        const _Float16* __restrict__ pa2, const _Float16* __restrict__ pb2,
        const float* __restrict__ ps2,
        float* __restrict__ out, int N) {
    constexpr int IT = 2;

    const int tid  = threadIdx.x;
    const int lane = tid & 63;
    const int w    = tid >> 6;

    int bid = blockIdx.x;
    const int CB      = N / 256;          // col-blocks per batch (IT=2: 256 cols/block)
    const int per_dir = BATCH * CB * NJ;
    const int dir = bid / per_dir;   bid %= per_dir;
    const int b   = bid / (CB * NJ); bid %= (CB * NJ);
    const int cb  = bid / NJ;
    const int js  = bid % NJ;

    const _Float16* pstream = dir ? pa1 : pa2;
    const _Float16* pheld   = dir ? pb2 : pb1;
    const float*    phps    = dir ? ps2 : ps1;
    float* outd = out + (size_t)dir * BATCH * N + (size_t)b * N;

    // Held B-fragments: 8B per lane, 2 tiles of 32 cols.
    const int colbase = cb * 256 + w * 64;
    const uint2* gh = (const uint2*)pheld;
    half4v bf[IT];
    #pragma unroll
    for (int it = 0; it < IT; ++it) {
        const int c = colbase + it * 32 + (lane & 31);
        bf[it] = __builtin_bit_cast(half4v, gh[(size_t)(b * N + c) * 2 + (lane >> 5)]);
    }

    f32x16 rmin16[IT];
    #pragma unroll
    for (int it = 0; it < IT; ++it)
        #pragma unroll
        for (int e = 0; e < 16; ++e)
            rmin16[it][e] = FLT_MAX;

    f32x16 cz;
    #pragma unroll
    for (int e = 0; e < 16; ++e) cz[e] = 0.0f;

    const int jseg   = N / NJ;
    const int ntiles = jseg / 32;
    const uint2* gs  = (const uint2*)pstream;
    const size_t abase = (size_t)(b * N + js * jseg) * 2
                       + (size_t)(lane & 31) * 2 + (lane >> 5);

    #pragma unroll 2
    for (int tt = 0; tt < ntiles; ++tt) {
        const half4v a = __builtin_bit_cast(half4v, gs[abase + (size_t)tt * 64]);
        #pragma unroll
        for (int it = 0; it < IT; ++it) {
            const f32x16 d = __builtin_amdgcn_mfma_f32_32x32x8f16(a, bf[it], cz, 0, 0, 0);
            // 16 independent v_min, no horizontal tree, no serial chain.
            rmin16[it] = __builtin_elementwise_min(rmin16[it], d);
        }
    }

    // epilogue (once per wave): fold 16-wide acc, combine row-halves,
    // add src |p|^2 (fp32 exact), atomicMin.
    #pragma unroll
    for (int it = 0; it < IT; ++it) {
        const float f = fold16(rmin16[it]);
        const float v = fminf(f, __shfl_xor(f, 32, 64));
        if (lane < 32) {
            const int c = colbase + it * 32 + lane;
            const float dfin = fmaxf(v + phps[(size_t)b * N + c], 0.0f);
            atomicMin((int*)&outd[c], __float_as_int(dfin));
        }
    }
}

// ================= fallback: R6 pk-fma path =================
__global__ void chamfer_prep(const float* __restrict__ xyz1,
                             const float* __restrict__ xyz2,
                             float4* __restrict__ pk1,
                             float4* __restrict__ pk2,
                             float* __restrict__ out,
                             int n1, int n2, int out_n) {
    int i = blockIdx.x * blockDim.x + threadIdx.x;
    if (i < n1) {
        float x = xyz1[3 * (size_t)i], y = xyz1[3 * (size_t)i + 1], z = xyz1[3 * (size_t)i + 2];
        pk1[i] = make_float4(-2.f * x, -2.f * y, -2.f * z, fmaf(x, x, fmaf(y, y, z * z)));
    }
    if (i < n2) {
        float x = xyz2[3 * (size_t)i], y = xyz2[3 * (size_t)i + 1], z = xyz2[3 * (size_t)i + 2];
        pk2[i] = make_float4(-2.f * x, -2.f * y, -2.f * z, fmaf(x, x, fmaf(y, y, z * z)));
    }
    if (i < out_n) out[i] = FLT_MAX;
}

template<int TPB, int CHUNK, int P>
__global__ __launch_bounds__(TPB) void chamfer_fused(
        const float* __restrict__ xyz1, const float* __restrict__ xyz2,
        const float4* __restrict__ pk1, const float4* __restrict__ pk2,
        float* __restrict__ out, int N, int M, int blocks_dir0) {
    __shared__ float4 s[CHUNK];
    int bid = blockIdx.x;
    const int dir = (bid >= blocks_dir0) ? 1 : 0;
    if (dir) bid -= blocks_dir0;
    const int Nsrc = dir ? M : N;
    const int Mdst = dir ? N : M;
    const float* src   = dir ? xyz2 : xyz1;
    const float4* dstp = dir ? pk1  : pk2;
    float* outd        = dir ? (out + (size_t)BATCH * N) : out;
    const int YT = Nsrc / (TPB * P);
    const int Z  = Mdst / CHUNK;
    const int b  = bid / (YT * Z);
    const int r  = bid % (YT * Z);
    const int yt = r / Z;
    const int z  = r % Z;
    const float4* dchunk = dstp + (size_t)b * Mdst + (size_t)z * CHUNK;
    for (int t = threadIdx.x; t < CHUNK / 2; t += TPB) {
        const float4 q0 = dchunk[2 * t];
        const float4 q1 = dchunk[2 * t + 1];
        s[2 * t]     = make_float4(q0.x, q1.x, q0.y, q1.y);
        s[2 * t + 1] = make_float4(q0.z, q1.z, q0.w, q1.w);
    }
    const int i0 = yt * (TPB * P) + threadIdx.x;
    f32x2 px[P], py[P], pz[P];
    float psq[P], m[P];
    #pragma unroll
    for (int k = 0; k < P; ++k) {
        const int i = i0 + k * TPB;
        const float* p = src + ((size_t)b * Nsrc + i) * 3;
        const float x = p[0], y = p[1], zc = p[2];
        px[k] = (f32x2){x, x}; py[k] = (f32x2){y, y}; pz[k] = (f32x2){zc, zc};
        psq[k] = fmaf(x, x, fmaf(y, y, zc * zc));
        m[k] = FLT_MAX;
    }
    __syncthreads();
    #pragma unroll 8
    for (int jj = 0; jj < CHUNK / 2; ++jj) {
        const float4 A = s[2 * jj];
        const float4 B = s[2 * jj + 1];
        const f32x2 xq = (f32x2){A.x, A.y};
        const f32x2 yq = (f32x2){A.z, A.w};
        const f32x2 zq = (f32x2){B.x, B.y};
        const f32x2 wq = (f32x2){B.z, B.w};
        #pragma unroll
        for (int k = 0; k < P; ++k) {
            const f32x2 e = __builtin_elementwise_fma(xq, px[k],
                             __builtin_elementwise_fma(yq, py[k],
                              __builtin_elementwise_fma(zq, pz[k], wq)));
            m[k] = fminf(fminf(m[k], e.x), e.y);
        }
    }
    #pragma unroll
    for (int k = 0; k < P; ++k) {
        const int i = i0 + k * TPB;
        const float d = fmaxf(psq[k] + m[k], 0.0f);
        atomicMin((int*)&outd[(size_t)b * Nsrc + i], __float_as_int(d));
    }
}

extern "C" void kernel_launch(void* const* d_in, const int* in_sizes, int n_in,
                              void* d_out, int out_size, void* d_ws, size_t ws_size,
                              hipStream_t stream) {
    const float* xyz1 = (const float*)d_in[0];
    const float* xyz2 = (const float*)d_in[1];
    float* out = (float*)d_out;

    const int N = in_sizes[0] / (BATCH * 3);  // 8192
    const int M = in_sizes[1] / (BATCH * 3);  // 8192
    const int n1 = BATCH * N, n2 = BATCH * M;

    constexpr int TPB = 256;
    constexpr int NJ = 16;

    // ws layout: pa1|pb1|pa2|pb2 (16B/pt each), then ps1|ps2 (4B/pt)
    const size_t need = ((size_t)n1 + (size_t)n2) * 36;
    const bool mfma_ok = (N == M) && (N % 256 == 0) && (N % (NJ * 32) == 0) &&
                         (ws_size >= need);

    if (mfma_ok) {
        _Float16* pa1 = (_Float16*)d_ws;
        _Float16* pb1 = pa1 + (size_t)n1 * 8;
        _Float16* pa2 = pb1 + (size_t)n1 * 8;
        _Float16* pb2 = pa2 + (size_t)n2 * 8;
        float* ps1 = (float*)(pb2 + (size_t)n2 * 8);
        float* ps2 = ps1 + n1;

        int prep_n = out_size > n1 ? out_size : n1;
        if (n2 > prep_n) prep_n = n2;
        prep_k8<<<(prep_n + TPB - 1) / TPB, TPB, 0, stream>>>(
            xyz1, xyz2, pa1, pb1, ps1, pa2, pb2, ps2, out, n1, n2, out_size);

        const int grid = 2 * BATCH * (N / 256) * NJ;   // 4096
        chamfer_k8<NJ><<<grid, TPB, 0, stream>>>(
            pa1, pb1, ps1, pa2, pb2, ps2, out, N);
        return;
    }

    // fallback: R6 pk-fma path
    constexpr int CHUNK = 128;
    constexpr int P = 8;
    const size_t needf = ((size_t)n1 + (size_t)n2) * sizeof(float4);
    if (ws_size >= needf && (N % (TPB * P) == 0) && (M % (TPB * P) == 0) &&
        (N % CHUNK == 0) && (M % CHUNK == 0)) {
        float4* pk1 = (float4*)d_ws;
        float4* pk2 = pk1 + n1;
        int prep_n = out_size > n1 ? out_size : n1;
        if (n2 > prep_n) prep_n = n2;
        chamfer_prep<<<(prep_n + TPB - 1) / TPB, TPB, 0, stream>>>(
            xyz1, xyz2, pk1, pk2, out, n1, n2, out_size);
        const int blocks_dir0 = BATCH * (N / (TPB * P)) * (M / CHUNK);
        const int blocks_dir1 = BATCH * (M / (TPB * P)) * (N / CHUNK);
        chamfer_fused<TPB, CHUNK, P><<<blocks_dir0 + blocks_dir1, TPB, 0, stream>>>(
            xyz1, xyz2, pk1, pk2, out, N, M, blocks_dir0);
    }
}

// Round 20
// 29.285 us; speedup vs baseline: 2.0948x; 2.0948x over previous
//
#include <hip/hip_runtime.h>
#include <float.h>

#define BATCH 4

typedef _Float16 half4v __attribute__((ext_vector_type(4)));
typedef _Float16 half8 __attribute__((ext_vector_type(8)));
typedef float f32x16 __attribute__((ext_vector_type(16)));
typedef float f32x2 __attribute__((ext_vector_type(2)));

// ================= MFMA K=8 path (R16 structure, R20 = asm MFMA + nops) ====
// E[j,i] = qs_j - 2 q_j . h_pi   via K=8 fp16 slots:
//  A[j] (scan side) = [hqx,hqy,hqz, eqx,eqy,eqz, qs_h, qs_e]
//  B[i] (held side) = [-2hpx,-2hpy,-2hpz, -2hpx,-2hpy,-2hpz, 1, 1]
// D[j,i] = E + |p_i|^2 added in fp32 in the EPILOGUE. Dropped -2q.e_p ~1.6e-2
// << 0.0675 threshold (R16/R18 measured absmax 0.0156).
//
// R20: asm v_mfma with "=&v" dst — "v" cannot be AGPR, so the min tree reads
// D directly (deletes the 16x v_accvgpr_read per MFMA that R19 exposed:
// elementwise-min into AGPR acc doubled VALU busy; VGPR_Count=32 proved the
// f32x16 state lives in AGPRs). R17 failed ONLY on the missing MFMA->VALU
// hazard wait-states (no HW interlock; absmax 2.41 = race): fixed here with
// 3x s_nop 7 (24 wait states >= ~18 required for 16-pass MFMA) inside the
// asm block. s_nop issues on the scalar pipe; other resident waves fill the
// cycles, so cost ~0 at 4+ waves/SIMD.

__global__ void prep_k8(const float* __restrict__ x1, const float* __restrict__ x2,
                        _Float16* __restrict__ pa1, _Float16* __restrict__ pb1, float* __restrict__ ps1,
                        _Float16* __restrict__ pa2, _Float16* __restrict__ pb2, float* __restrict__ ps2,
                        float* __restrict__ out, int n1, int n2, int outn) {
    const int i = blockIdx.x * blockDim.x + threadIdx.x;
    const _Float16 one = (_Float16)1.0f;

    #pragma unroll
    for (int which = 0; which < 2; ++which) {
        const int n = which ? n2 : n1;
        if (i >= n) continue;
        const float* xp = (which ? x2 : x1) + 3 * (size_t)i;
        _Float16* pa = (which ? pa2 : pa1) + 8 * (size_t)i;
        _Float16* pb = (which ? pb2 : pb1) + 8 * (size_t)i;
        float* ps    = (which ? ps2 : ps1);

        const float x = xp[0], y = xp[1], z = xp[2];
        const _Float16 hx = (_Float16)x, hy = (_Float16)y, hz = (_Float16)z;
        const _Float16 ex = (_Float16)(x - (float)hx);
        const _Float16 ey = (_Float16)(y - (float)hy);
        const _Float16 ez = (_Float16)(z - (float)hz);
        const float sq = fmaf(x, x, fmaf(y, y, z * z));
        const _Float16 qh = (_Float16)sq;
        const _Float16 qe = (_Float16)(sq - (float)qh);
        const _Float16 tx = (_Float16)(-2.0f * (float)hx);
        const _Float16 ty = (_Float16)(-2.0f * (float)hy);
        const _Float16 tz = (_Float16)(-2.0f * (float)hz);

        *(half8*)pa = (half8){hx, hy, hz, ex, ey, ez, qh, qe};   // A-form, 16B
        *(half8*)pb = (half8){tx, ty, tz, tx, ty, tz, one, one}; // B-form, 16B
        ps[i] = sq;                                              // fp32 exact
    }
    if (i < outn) out[i] = FLT_MAX;
}

// Fold 16 fresh values + running min into one scalar: 8 v_min3-class ops.
__device__ inline float min16_into(float r, const f32x16 d) {
    const float t0 = fminf(fminf(d[0],  d[1]),  d[2]);
    const float t1 = fminf(fminf(d[3],  d[4]),  d[5]);
    const float t2 = fminf(fminf(d[6],  d[7]),  d[8]);
    const float t3 = fminf(fminf(d[9],  d[10]), d[11]);
    const float t4 = fminf(fminf(d[12], d[13]), d[14]);
    const float u0 = fminf(fminf(t0, t1), t2);
    const float u1 = fminf(fminf(t3, t4), d[15]);
    return fminf(fminf(r, u0), u1);
}

// R20: LDS-free (R13-proven), K=8, IT=4, asm-VGPR MFMA + hazard nops.
template<int NJ>
__global__ __launch_bounds__(256) void chamfer_k8(
        const _Float16* __restrict__ pa1, const _Float16* __restrict__ pb1,
        const float* __restrict__ ps1,
        const _Float16* __restrict__ pa2, const _Float16* __restrict__ pb2,
        const float* __restrict__ ps2,
        float* __restrict__ out, int N) {
    constexpr int IT = 4;

    const int tid  = threadIdx.x;
    const int lane = tid & 63;
    const int w    = tid >> 6;

    int bid = blockIdx.x;
    const int CB      = N / 512;          // col-blocks per batch
    const int per_dir = BATCH * CB * NJ;
    const int dir = bid / per_dir;   bid %= per_dir;
    const int b   = bid / (CB * NJ); bid %= (CB * NJ);
    const int cb  = bid / NJ;
    const int js  = bid % NJ;

    const _Float16* pstream = dir ? pa1 : pa2;
    const _Float16* pheld   = dir ? pb2 : pb1;
    const float*    phps    = dir ? ps2 : ps1;
    float* outd = out + (size_t)dir * BATCH * N + (size_t)b * N;

    // Held B-fragments: 8B per lane, 4 tiles of 32 cols.
    const int colbase = cb * 512 + w * 128;
    const uint2* gh = (const uint2*)pheld;
    half4v bf[IT];
    #pragma unroll
    for (int it = 0; it < IT; ++it) {
        const int c = colbase + it * 32 + (lane & 31);
        bf[it] = __builtin_bit_cast(half4v, gh[(size_t)(b * N + c) * 2 + (lane >> 5)]);
    }

    float rmin[IT];
    #pragma unroll
    for (int it = 0; it < IT; ++it) rmin[it] = FLT_MAX;

    f32x16 cz;
    #pragma unroll
    for (int e = 0; e < 16; ++e) cz[e] = 0.0f;

    const int jseg   = N / NJ;
    const int ntiles = jseg / 32;
    const uint2* gs  = (const uint2*)pstream;
    const size_t abase = (size_t)(b * N + js * jseg) * 2
                       + (size_t)(lane & 31) * 2 + (lane >> 5);

    #pragma unroll 2
    for (int tt = 0; tt < ntiles; ++tt) {
        const half4v a = __builtin_bit_cast(half4v, gs[abase + (size_t)tt * 64]);
        #pragma unroll
        for (int it = 0; it < IT; ++it) {
            f32x16 d;
            // dst "=&v" => arch VGPRs (no AGPR, no accvgpr_read fan-out).
            // 3x s_nop 7 = 24 wait states covers the MFMA->VALU RAW hazard
            // (~18 for a 16-pass MFMA) that R17 missed. Scalar-pipe nops;
            // co-resident waves fill the cycles.
            asm volatile("v_mfma_f32_32x32x8_f16 %0, %1, %2, %3\n\t"
                         "s_nop 7\n\t"
                         "s_nop 7\n\t"
                         "s_nop 7"
                         : "=&v"(d)
                         : "v"(a), "v"(bf[it]), "v"(cz));
            rmin[it] = min16_into(rmin[it], d);
        }
    }

    // epilogue: combine row-halves, add src |p|^2 (fp32 exact), atomicMin.
    #pragma unroll
    for (int it = 0; it < IT; ++it) {
        const float v = fminf(rmin[it], __shfl_xor(rmin[it], 32, 64));
        if (lane < 32) {
            const int c = colbase + it * 32 + lane;
            const float dfin = fmaxf(v + phps[(size_t)b * N + c], 0.0f);
            atomicMin((int*)&outd[c], __float_as_int(dfin));
        }
    }
}

// ================= fallback: R6 pk-fma path =================
__global__ void chamfer_prep(const float* __restrict__ xyz1,
                             const float* __restrict__ xyz2,
                             float4* __restrict__ pk1,
                             float4* __restrict__ pk2,
                             float* __restrict__ out,
                             int n1, int n2, int out_n) {
    int i = blockIdx.x * blockDim.x + threadIdx.x;
    if (i < n1) {
        float x = xyz1[3 * (size_t)i], y = xyz1[3 * (size_t)i + 1], z = xyz1[3 * (size_t)i + 2];
        pk1[i] = make_float4(-2.f * x, -2.f * y, -2.f * z, fmaf(x, x, fmaf(y, y, z * z)));
    }
    if (i < n2) {
        float x = xyz2[3 * (size_t)i], y = xyz2[3 * (size_t)i + 1], z = xyz2[3 * (size_t)i + 2];
        pk2[i] = make_float4(-2.f * x, -2.f * y, -2.f * z, fmaf(x, x, fmaf(y, y, z * z)));
    }
    if (i < out_n) out[i] = FLT_MAX;
}

template<int TPB, int CHUNK, int P>
__global__ __launch_bounds__(TPB) void chamfer_fused(
        const float* __restrict__ xyz1, const float* __restrict__ xyz2,
        const float4* __restrict__ pk1, const float4* __restrict__ pk2,
        float* __restrict__ out, int N, int M, int blocks_dir0) {
    __shared__ float4 s[CHUNK];
    int bid = blockIdx.x;
    const int dir = (bid >= blocks_dir0) ? 1 : 0;
    if (dir) bid -= blocks_dir0;
    const int Nsrc = dir ? M : N;
    const int Mdst = dir ? N : M;
    const float* src   = dir ? xyz2 : xyz1;
    const float4* dstp = dir ? pk1  : pk2;
    float* outd        = dir ? (out + (size_t)BATCH * N) : out;
    const int YT = Nsrc / (TPB * P);
    const int Z  = Mdst / CHUNK;
    const int b  = bid / (YT * Z);
    const int r  = bid % (YT * Z);
    const int yt = r / Z;
    const int z  = r % Z;
    const float4* dchunk = dstp + (size_t)b * Mdst + (size_t)z * CHUNK;
    for (int t = threadIdx.x; t < CHUNK / 2; t += TPB) {
        const float4 q0 = dchunk[2 * t];
        const float4 q1 = dchunk[2 * t + 1];
        s[2 * t]     = make_float4(q0.x, q1.x, q0.y, q1.y);
        s[2 * t + 1] = make_float4(q0.z, q1.z, q0.w, q1.w);
    }
    const int i0 = yt * (TPB * P) + threadIdx.x;
    f32x2 px[P], py[P], pz[P];
    float psq[P], m[P];
    #pragma unroll
    for (int k = 0; k < P; ++k) {
        const int i = i0 + k * TPB;
        const float* p = src + ((size_t)b * Nsrc + i) * 3;
        const float x = p[0], y = p[1], zc = p[2];
        px[k] = (f32x2){x, x}; py[k] = (f32x2){y, y}; pz[k] = (f32x2){zc, zc};
        psq[k] = fmaf(x, x, fmaf(y, y, zc * zc));
        m[k] = FLT_MAX;
    }
    __syncthreads();
    #pragma unroll 8
    for (int jj = 0; jj < CHUNK / 2; ++jj) {
        const float4 A = s[2 * jj];
        const float4 B = s[2 * jj + 1];
        const f32x2 xq = (f32x2){A.x, A.y};
        const f32x2 yq = (f32x2){A.z, A.w};
        const f32x2 zq = (f32x2){B.x, B.y};
        const f32x2 wq = (f32x2){B.z, B.w};
        #pragma unroll
        for (int k = 0; k < P; ++k) {
            const f32x2 e = __builtin_elementwise_fma(xq, px[k],
                             __builtin_elementwise_fma(yq, py[k],
                              __builtin_elementwise_fma(zq, pz[k], wq)));
            m[k] = fminf(fminf(m[k], e.x), e.y);
        }
    }
    #pragma unroll
    for (int k = 0; k < P; ++k) {
        const int i = i0 + k * TPB;
        const float d = fmaxf(psq[k] + m[k], 0.0f);
        atomicMin((int*)&outd[(size_t)b * Nsrc + i], __float_as_int(d));
    }
}

extern "C" void kernel_launch(void* const* d_in, const int* in_sizes, int n_in,
                              void* d_out, int out_size, void* d_ws, size_t ws_size,
                              hipStream_t stream) {
    const float* xyz1 = (const float*)d_in[0];
    const float* xyz2 = (const float*)d_in[1];
    float* out = (float*)d_out;

    const int N = in_sizes[0] / (BATCH * 3);  // 8192
    const int M = in_sizes[1] / (BATCH * 3);  // 8192
    const int n1 = BATCH * N, n2 = BATCH * M;

    constexpr int TPB = 256;
    constexpr int NJ = 16;

    // ws layout: pa1|pb1|pa2|pb2 (16B/pt each), then ps1|ps2 (4B/pt)
    const size_t need = ((size_t)n1 + (size_t)n2) * 36;
    const bool mfma_ok = (N == M) && (N % 512 == 0) && (N % (NJ * 32) == 0) &&
                         (ws_size >= need);

    if (mfma_ok) {
        _Float16* pa1 = (_Float16*)d_ws;
        _Float16* pb1 = pa1 + (size_t)n1 * 8;
        _Float16* pa2 = pb1 + (size_t)n1 * 8;
        _Float16* pb2 = pa2 + (size_t)n2 * 8;
        float* ps1 = (float*)(pb2 + (size_t)n2 * 8);
        float* ps2 = ps1 + n1;

        int prep_n = out_size > n1 ? out_size : n1;
        if (n2 > prep_n) prep_n = n2;
        prep_k8<<<(prep_n + TPB - 1) / TPB, TPB, 0, stream>>>(
            xyz1, xyz2, pa1, pb1, ps1, pa2, pb2, ps2, out, n1, n2, out_size);

        const int grid = 2 * BATCH * (N / 512) * NJ;   // 2048
        chamfer_k8<NJ><<<grid, TPB, 0, stream>>>(
            pa1, pb1, ps1, pa2, pb2, ps2, out, N);
        return;
    }

    // fallback: R6 pk-fma path
    constexpr int CHUNK = 128;
    constexpr int P = 8;
    const size_t needf = ((size_t)n1 + (size_t)n2) * sizeof(float4);
    if (ws_size >= needf && (N % (TPB * P) == 0) && (M % (TPB * P) == 0) &&
        (N % CHUNK == 0) && (M % CHUNK == 0)) {
        float4* pk1 = (float4*)d_ws;
        float4* pk2 = pk1 + n1;
        int prep_n = out_size > n1 ? out_size : n1;
        if (n2 > prep_n) prep_n = n2;
        chamfer_prep<<<(prep_n + TPB - 1) / TPB, TPB, 0, stream>>>(
            xyz1, xyz2, pk1, pk2, out, n1, n2, out_size);
        const int blocks_dir0 = BATCH * (N / (TPB * P)) * (M / CHUNK);
        const int blocks_dir1 = BATCH * (M / (TPB * P)) * (N / CHUNK);
        chamfer_fused<TPB, CHUNK, P><<<blocks_dir0 + blocks_dir1, TPB, 0, stream>>>(
            xyz1, xyz2, pk1, pk2, out, N, M, blocks_dir0);
    }
}